// Round 8
// baseline (227.704 us; speedup 1.0000x reference)
//
#include <hip/hip_runtime.h>
#include <math.h>

#define IN_CH 128
#define HID 64
#define OUT_CH 10

typedef unsigned int uint32;
typedef unsigned char u8;
typedef unsigned short u16;
typedef unsigned short bf16u;
typedef __attribute__((ext_vector_type(8))) short bf16x8;
typedef __attribute__((ext_vector_type(4))) float f32x4;
typedef __attribute__((ext_vector_type(2))) float f32x2;

static __device__ inline bf16u f2bf(float f) {
    uint32 u = __float_as_uint(f);
    u += 0x7fff + ((u >> 16) & 1);          // round-nearest-even
    return (bf16u)(u >> 16);
}
static __device__ inline uint32 pack2(float a, float b) {
    return (uint32)f2bf(a) | ((uint32)f2bf(b) << 16);
}
static __device__ inline u8 f2fp8(float v) {
    uint32 p = __builtin_amdgcn_cvt_pk_fp8_f32(v, v, 0, false);
    return (u8)(p & 0xff);
}
// non-temporal helpers: mark streaming traffic so it does not evict the
// randomly-re-read y rows from the 4MiB per-XCD L2 (R5 PMC: agg0f
// FETCH_SIZE 23.7MB despite 3.2MB resident working set).
static __device__ inline u16 ldnt16(const u16* p) {
    return __builtin_nontemporal_load(p);
}
static __device__ inline int ldnt32(const int* p) {
    return __builtin_nontemporal_load(p);
}
// packed accumulate: 2 cvt + 2 v_pk_add_f32 per fp8x4
static __device__ inline void acc_fp8x4(uint32 u, f32x2& a01, f32x2& a23) {
    a01 += __builtin_amdgcn_cvt_pk_f32_fp8((int)u, false);
    a23 += __builtin_amdgcn_cvt_pk_f32_fp8((int)u, true);
}

// neighbor-sum: ONE node per 16-lane group. lane cc=lane&15 owns channels
// 4*cc..4*cc+3. 8-wide software pipeline: next 8 col indices load while
// current 8 y-gathers are in flight. col loads are non-temporal (streamed
// once); y8 loads are normal (the L2-resident set we protect).
static __device__ inline void gather_group(
    const uint32* __restrict__ y8, const u16* __restrict__ col,
    int rs, int re, int cc, f32x2& a01, f32x2& a23)
{
    int j = rs;
    if (j + 8 <= re) {
        int c0 = ldnt16(col + j),     c1 = ldnt16(col + j + 1),
            c2 = ldnt16(col + j + 2), c3 = ldnt16(col + j + 3),
            c4 = ldnt16(col + j + 4), c5 = ldnt16(col + j + 5),
            c6 = ldnt16(col + j + 6), c7 = ldnt16(col + j + 7);
        j += 8;
        while (j + 8 <= re) {
            int n0 = ldnt16(col + j),     n1 = ldnt16(col + j + 1),
                n2 = ldnt16(col + j + 2), n3 = ldnt16(col + j + 3),
                n4 = ldnt16(col + j + 4), n5 = ldnt16(col + j + 5),
                n6 = ldnt16(col + j + 6), n7 = ldnt16(col + j + 7);
            uint32 u0 = y8[(long)c0 * 16 + cc], u1 = y8[(long)c1 * 16 + cc],
                   u2 = y8[(long)c2 * 16 + cc], u3 = y8[(long)c3 * 16 + cc],
                   u4 = y8[(long)c4 * 16 + cc], u5 = y8[(long)c5 * 16 + cc],
                   u6 = y8[(long)c6 * 16 + cc], u7 = y8[(long)c7 * 16 + cc];
            acc_fp8x4(u0, a01, a23);
            acc_fp8x4(u1, a01, a23);
            acc_fp8x4(u2, a01, a23);
            acc_fp8x4(u3, a01, a23);
            acc_fp8x4(u4, a01, a23);
            acc_fp8x4(u5, a01, a23);
            acc_fp8x4(u6, a01, a23);
            acc_fp8x4(u7, a01, a23);
            c0 = n0; c1 = n1; c2 = n2; c3 = n3;
            c4 = n4; c5 = n5; c6 = n6; c7 = n7;
            j += 8;
        }
        uint32 u0 = y8[(long)c0 * 16 + cc], u1 = y8[(long)c1 * 16 + cc],
               u2 = y8[(long)c2 * 16 + cc], u3 = y8[(long)c3 * 16 + cc],
               u4 = y8[(long)c4 * 16 + cc], u5 = y8[(long)c5 * 16 + cc],
               u6 = y8[(long)c6 * 16 + cc], u7 = y8[(long)c7 * 16 + cc];
        acc_fp8x4(u0, a01, a23);
        acc_fp8x4(u1, a01, a23);
        acc_fp8x4(u2, a01, a23);
        acc_fp8x4(u3, a01, a23);
        acc_fp8x4(u4, a01, a23);
        acc_fp8x4(u5, a01, a23);
        acc_fp8x4(u6, a01, a23);
        acc_fp8x4(u7, a01, a23);
    }
    for (; j < re; ++j) {
        uint32 u = y8[(long)ldnt16(col + j) * 16 + cc];
        acc_fp8x4(u, a01, a23);
    }
}

// ---------- pure degree count (atomic with return -> pos u16) ----------
__global__ __launch_bounds__(256) void k_count(
    const int* __restrict__ dst, int* __restrict__ cnt,
    u16* __restrict__ pos, int E)
{
    int e = blockIdx.x * 256 + threadIdx.x;
    if (e < E) {
        int d = ldnt32(dst + e);
        u16 p = (u16)atomicAdd(&cnt[d], 1);
        __builtin_nontemporal_store(p, pos + e);
    }
}

// ---------- single-kernel scan: cnt[N] -> row_ptr[N+1] ----------
__global__ __launch_bounds__(256) void k_scan(
    const int* __restrict__ cnt, int* __restrict__ row_ptr,
    int* __restrict__ partials, int* __restrict__ counter, int N, int E, int nch)
{
    __shared__ int red[256];
    int tid = threadIdx.x;
    int bid = blockIdx.x;
    long base = (long)bid * 1024 + tid * 4;
    int v[4]; int s = 0;
    #pragma unroll
    for (int i = 0; i < 4; i++) {
        long idx = base + i;
        v[i] = (idx < N) ? cnt[idx] : 0;
        s += v[i];
    }
    red[tid] = s;
    __syncthreads();
    for (int off = 1; off < 256; off <<= 1) {
        int t = (tid >= off) ? red[tid - off] : 0;
        __syncthreads();
        red[tid] += t;
        __syncthreads();
    }
    int myexcl = red[tid] - s;
    if (tid == 255) {
        __hip_atomic_store(&partials[bid], red[255], __ATOMIC_RELEASE,
                           __HIP_MEMORY_SCOPE_AGENT);
        atomicAdd(counter, 1);
    }
    if (tid == 0) {
        while (__hip_atomic_load(counter, __ATOMIC_ACQUIRE,
                                 __HIP_MEMORY_SCOPE_AGENT) < nch) { }
    }
    __syncthreads();
    int off = 0;
    for (int i = tid; i < bid; i += 256)
        off += __hip_atomic_load(&partials[i], __ATOMIC_RELAXED,
                                 __HIP_MEMORY_SCOPE_AGENT);
    __syncthreads();
    red[tid] = off;
    __syncthreads();
    for (int o = 128; o; o >>= 1) {
        if (tid < o) red[tid] += red[tid + o];
        __syncthreads();
    }
    int run = red[0] + myexcl;
    #pragma unroll
    for (int i = 0; i < 4; i++) {
        long idx = base + i;
        if (idx < N) row_ptr[idx] = run;
        run += v[i];
    }
    if (bid == 0 && tid == 0) row_ptr[N] = E;
}

// ---------- fused: CSR place (fire-and-forget scatter) + lin0 MFMA ----------
// lin0 loads its A-fragments DIRECTLY from x (no LDS/barriers). place's
// streaming edge reads are non-temporal.
__global__ __launch_bounds__(256, 6) void k_placelin0(
    const int* __restrict__ src, const int* __restrict__ dst,
    const int* __restrict__ row_ptr, const u16* __restrict__ pos,
    u16* __restrict__ col,
    const float4* __restrict__ x4, const float* __restrict__ w,
    u8* __restrict__ y, int N, int E)
{
    int gt = blockIdx.x * 256 + threadIdx.x;
    for (int e = gt; e < E; e += gridDim.x * 256) {
        int d = ldnt32(dst + e);
        u16 p = ldnt16(pos + e);
        int s = ldnt32(src + e);
        col[row_ptr[d] + p] = (u16)s;
    }

    int tid = threadIdx.x;
    int wid = tid >> 6, lane = tid & 63;
    int quad = lane >> 4, n15 = lane & 15;
    int mycol = wid * 16 + n15;
    bf16x8 fb[4];
    #pragma unroll
    for (int s = 0; s < 4; s++)
        #pragma unroll
        for (int j = 0; j < 8; j++)
            fb[s][j] = (short)f2bf(w[(s * 32 + quad * 8 + j) * HID + mycol]);
    for (long g0 = (long)blockIdx.x * 16; g0 < N; g0 += (long)gridDim.x * 16) {
        long node = g0 + n15;
        if (node >= N) node = N - 1;    // defensive clamp (N%16==0 -> no-op)
        f32x4 acc = {0.f, 0.f, 0.f, 0.f};
        #pragma unroll
        for (int s = 0; s < 4; s++) {
            float4 v0 = x4[node * 32 + s * 8 + quad * 2];
            float4 v1 = x4[node * 32 + s * 8 + quad * 2 + 1];
            bf16x8 a;
            a[0] = (short)f2bf(v0.x); a[1] = (short)f2bf(v0.y);
            a[2] = (short)f2bf(v0.z); a[3] = (short)f2bf(v0.w);
            a[4] = (short)f2bf(v1.x); a[5] = (short)f2bf(v1.y);
            a[6] = (short)f2bf(v1.z); a[7] = (short)f2bf(v1.w);
            acc = __builtin_amdgcn_mfma_f32_16x16x32_bf16(a, fb[s], acc, 0, 0, 0);
        }
        #pragma unroll
        for (int r = 0; r < 4; r++) {
            long n = g0 + quad * 4 + r;
            if (n < N) y[n * HID + mycol] = f2fp8(acc[r]);
        }
    }
}

// ---------- agg0f (MFMA): t=relu((1+e)y0+Σnbr+b0a); y1=relu(t@w0b+b0b)@w1a ----
// y1 stores non-temporal: within this kernel y1 is write-only streaming; nt
// keeps y0 resident in L2 (the gather's random re-read set). agg1 refills
// y1 from L3 on first touch.
__global__ __launch_bounds__(256, 6) void k_agg0f(
    const uint32* __restrict__ y8, const int* __restrict__ row_ptr,
    const u16* __restrict__ col, const float* __restrict__ epsp,
    const float* __restrict__ ba, const float* __restrict__ wb,
    const float* __restrict__ bb, const float* __restrict__ w1a,
    u8* __restrict__ y1, int N)
{
    __shared__ __align__(16) uint32 t32[16 * 36];
    __shared__ __align__(16) uint32 h32[16 * 36];
    int tid = threadIdx.x;
    int wid = tid >> 6, lane = tid & 63;
    int cc = lane & 15, h = lane >> 4;
    int quad = lane >> 4, n15 = lane & 15;
    int n0 = wid * 4;
    int mycol = wid * 16 + n15;
    float e = 1.f + epsp[0];
    float4 bav = ((const float4*)ba)[cc];
    float bbv = bb[mycol];
    bf16x8 fb[2], f1[2];
    #pragma unroll
    for (int s = 0; s < 2; s++)
        #pragma unroll
        for (int j = 0; j < 8; j++) {
            fb[s][j] = (short)f2bf(wb[(s * 32 + quad * 8 + j) * HID + mycol]);
            f1[s][j] = (short)f2bf(w1a[(s * 32 + quad * 8 + j) * HID + mycol]);
        }
    for (long g0 = (long)blockIdx.x * 16; g0 < N; g0 += (long)gridDim.x * 16) {
        long node = g0 + n0 + h;        // each 16-lane group owns one node
        if (node < N) {
            int rs = row_ptr[node], re = row_ptr[node + 1];
            uint32 us = y8[node * 16 + cc];
            f32x2 a01 = {0.f, 0.f}, a23 = {0.f, 0.f};
            gather_group(y8, col, rs, re, cc, a01, a23);
            f32x2 lo = __builtin_amdgcn_cvt_pk_f32_fp8((int)us, false);
            f32x2 hi = __builtin_amdgcn_cvt_pk_f32_fp8((int)us, true);
            a01 += lo * e;              // v_pk_fma_f32
            a23 += hi * e;
            t32[(n0 + h) * 36 + 2 * cc]     = pack2(fmaxf(a01.x + bav.x, 0.f),
                                                    fmaxf(a01.y + bav.y, 0.f));
            t32[(n0 + h) * 36 + 2 * cc + 1] = pack2(fmaxf(a23.x + bav.z, 0.f),
                                                    fmaxf(a23.y + bav.w, 0.f));
        }
        __syncthreads();
        f32x4 acc = {bbv, bbv, bbv, bbv};
        {
            bf16x8 a0 = *(const bf16x8*)((const char*)t32 + n15 * 144 + quad * 16);
            bf16x8 a1 = *(const bf16x8*)((const char*)t32 + n15 * 144 + 64 + quad * 16);
            acc = __builtin_amdgcn_mfma_f32_16x16x32_bf16(a0, fb[0], acc, 0, 0, 0);
            acc = __builtin_amdgcn_mfma_f32_16x16x32_bf16(a1, fb[1], acc, 0, 0, 0);
        }
        #pragma unroll
        for (int r = 0; r < 4; r++)
            ((short*)h32)[(quad * 4 + r) * 72 + mycol] = (short)f2bf(fmaxf(acc[r], 0.f));
        __syncthreads();
        f32x4 acc2 = {0.f, 0.f, 0.f, 0.f};
        {
            bf16x8 a0 = *(const bf16x8*)((const char*)h32 + n15 * 144 + quad * 16);
            bf16x8 a1 = *(const bf16x8*)((const char*)h32 + n15 * 144 + 64 + quad * 16);
            acc2 = __builtin_amdgcn_mfma_f32_16x16x32_bf16(a0, f1[0], acc2, 0, 0, 0);
            acc2 = __builtin_amdgcn_mfma_f32_16x16x32_bf16(a1, f1[1], acc2, 0, 0, 0);
        }
        #pragma unroll
        for (int r = 0; r < 4; r++) {
            long n = g0 + quad * 4 + r;
            if (n < N)
                __builtin_nontemporal_store(f2fp8(acc2[r]), y1 + n * HID + mycol);
        }
    }
}

// ---------- agg1 (MFMA): gather + MLP-b + pooling ----------
__global__ __launch_bounds__(256, 6) void k_agg1(
    const uint32* __restrict__ y8, const int* __restrict__ row_ptr,
    const u16* __restrict__ col, const float* __restrict__ epsp,
    const float* __restrict__ ba, const float* __restrict__ wb,
    const float* __restrict__ bb, const int* __restrict__ batch,
    float* __restrict__ pooled, int N)
{
    __shared__ __align__(16) uint32 t32[16 * 36];
    int tid = threadIdx.x;
    int wid = tid >> 6, lane = tid & 63;
    int cc = lane & 15, h = lane >> 4;
    int quad = lane >> 4, n15 = lane & 15;
    int n0 = wid * 4;
    int mycol = wid * 16 + n15;
    float e = 1.f + epsp[0];
    float4 bav = ((const float4*)ba)[cc];
    float bbv = bb[mycol];
    bf16x8 fb[2];
    #pragma unroll
    for (int s = 0; s < 2; s++)
        #pragma unroll
        for (int j = 0; j < 8; j++)
            fb[s][j] = (short)f2bf(wb[(s * 32 + quad * 8 + j) * HID + mycol]);
    for (long g0 = (long)blockIdx.x * 16; g0 < N; g0 += (long)gridDim.x * 16) {
        long node = g0 + n0 + h;        // each 16-lane group owns one node
        if (node < N) {
            int rs = row_ptr[node], re = row_ptr[node + 1];
            uint32 us = y8[node * 16 + cc];
            f32x2 a01 = {0.f, 0.f}, a23 = {0.f, 0.f};
            gather_group(y8, col, rs, re, cc, a01, a23);
            f32x2 lo = __builtin_amdgcn_cvt_pk_f32_fp8((int)us, false);
            f32x2 hi = __builtin_amdgcn_cvt_pk_f32_fp8((int)us, true);
            a01 += lo * e;
            a23 += hi * e;
            t32[(n0 + h) * 36 + 2 * cc]     = pack2(fmaxf(a01.x + bav.x, 0.f),
                                                    fmaxf(a01.y + bav.y, 0.f));
            t32[(n0 + h) * 36 + 2 * cc + 1] = pack2(fmaxf(a23.x + bav.z, 0.f),
                                                    fmaxf(a23.y + bav.w, 0.f));
        }
        __syncthreads();
        f32x4 acc = {bbv, bbv, bbv, bbv};
        {
            bf16x8 a0 = *(const bf16x8*)((const char*)t32 + n15 * 144 + quad * 16);
            bf16x8 a1 = *(const bf16x8*)((const char*)t32 + n15 * 144 + 64 + quad * 16);
            acc = __builtin_amdgcn_mfma_f32_16x16x32_bf16(a0, fb[0], acc, 0, 0, 0);
            acc = __builtin_amdgcn_mfma_f32_16x16x32_bf16(a1, fb[1], acc, 0, 0, 0);
        }
        float rv[4];
        #pragma unroll
        for (int r = 0; r < 4; r++) rv[r] = fmaxf(acc[r], 0.f);
        int nv = (int)((N - g0) < 16 ? (N - g0) : 16);
        int bf_ = batch[g0], bl_ = batch[g0 + nv - 1];
        if (bf_ == bl_) {
            float s = 0.f;
            #pragma unroll
            for (int r = 0; r < 4; r++)
                if (quad * 4 + r < nv) s += rv[r];
            s += __shfl_xor(s, 16);
            s += __shfl_xor(s, 32);
            if (quad == 0)
                atomicAdd(&pooled[(long)bf_ * HID + mycol], s);
        } else {
            #pragma unroll
            for (int r = 0; r < 4; r++) {
                long n = g0 + quad * 4 + r;
                if (n < N)
                    atomicAdd(&pooled[(long)batch[n] * HID + mycol], rv[r]);
            }
        }
        __syncthreads();
    }
}

// ---------- head ----------
__global__ __launch_bounds__(64) void k_head(
    const float* __restrict__ pooled, const float* __restrict__ fcw,
    const float* __restrict__ fcb, float* __restrict__ out)
{
    int g = blockIdx.x;
    int l = threadIdx.x;
    float logit = -INFINITY;
    if (l < OUT_CH) {
        float acc = fcb[l];
        #pragma unroll
        for (int k = 0; k < HID; k++)
            acc = fmaf(pooled[g * HID + k], fcw[k * OUT_CH + l], acc);
        logit = acc;
    }
    float m = logit;
    #pragma unroll
    for (int off = 32; off; off >>= 1) m = fmaxf(m, __shfl_xor(m, off));
    float ex = (l < OUT_CH) ? expf(logit - m) : 0.0f;
    float s = ex;
    #pragma unroll
    for (int off = 32; off; off >>= 1) s += __shfl_xor(s, off);
    if (l < OUT_CH) out[g * OUT_CH + l] = logit - m - logf(s);
}

extern "C" void kernel_launch(void* const* d_in, const int* in_sizes, int n_in,
                              void* d_out, int out_size, void* d_ws, size_t ws_size,
                              hipStream_t stream) {
    const float* x    = (const float*)d_in[0];
    const int*   ei   = (const int*)d_in[1];
    const int*   batch= (const int*)d_in[2];
    const float* eps0 = (const float*)d_in[3];
    const float* w0a  = (const float*)d_in[4];
    const float* b0a  = (const float*)d_in[5];
    const float* w0b  = (const float*)d_in[6];
    const float* b0b  = (const float*)d_in[7];
    const float* eps1 = (const float*)d_in[8];
    const float* w1a  = (const float*)d_in[9];
    const float* b1a  = (const float*)d_in[10];
    const float* w1b  = (const float*)d_in[11];
    const float* b1b  = (const float*)d_in[12];
    const float* fcw  = (const float*)d_in[13];
    const float* fcb  = (const float*)d_in[14];
    float* out = (float*)d_out;

    const int N = in_sizes[0] / IN_CH;       // 50000
    const int E = in_sizes[1] / 2;           // 800000
    const int G = out_size / OUT_CH;         // 512
    const int* src = ei;
    const int* dst = ei + E;

    // workspace layout (bytes):
    // [0, 200064)            row_ptr  (N+1 ints)
    // [200064, 1800064)      col      (E u16)
    // [3400064, 6600064)     y0       (N*64 fp8)
    // [6600064, 9800064)     y1       (N*64 fp8)
    // [9800064, 10000064)    cnt      (N ints)
    // [10000064, 10000068)   counter
    // [10000128, 10000384)   partials (49 ints, padded)
    // [10000384, 10131456)   pooled   (G*64 fp32)
    // [10131456, 11731456)   pos      (E u16)
    char* ws = (char*)d_ws;
    int*    row_ptr  = (int*)(ws);
    u16*    colv     = (u16*)(ws + 200064);
    u8*     y0       = (u8*)(ws + 3400064);
    u8*     y1       = (u8*)(ws + 6600064);
    int*    cnt      = (int*)(ws + 9800064);
    int*    counter  = (int*)(ws + 10000064);
    int*    partials = (int*)(ws + 10000128);
    float*  pooled   = (float*)(ws + 10000384);
    u16*    pos      = (u16*)(ws + 10131456);

    // one memset covers cnt + counter + partials + pooled
    hipMemsetAsync(cnt, 0, 331392, stream);

    int eb = (E + 255) / 256;                   // 3125
    int nb = (N + 31) / 32;                     // 1563
    int nch = (N + 1023) / 1024;                // 49 blocks, all co-resident
    k_count<<<eb, 256, 0, stream>>>(dst, cnt, pos, E);
    k_scan<<<nch, 256, 0, stream>>>(cnt, row_ptr, partials, counter, N, E, nch);
    k_placelin0<<<nb, 256, 0, stream>>>(src, dst, row_ptr, pos, colv,
                                        (const float4*)x, w0a, y0, N, E);
    k_agg0f<<<nb, 256, 0, stream>>>((const uint32*)y0, row_ptr, colv, eps0,
                                    b0a, w0b, b0b, w1a, y1, N);
    k_agg1<<<nb, 256, 0, stream>>>((const uint32*)y1, row_ptr, colv, eps1,
                                   b1a, w1b, b1b, batch, pooled, N);
    k_head<<<G, 64, 0, stream>>>(pooled, fcw, fcb, out);
}

// Round 9
// 198.825 us; speedup vs baseline: 1.1452x; 1.1452x over previous
//
#include <hip/hip_runtime.h>
#include <math.h>

#define IN_CH 128
#define HID 64
#define OUT_CH 10

typedef unsigned int uint32;
typedef unsigned char u8;
typedef unsigned short bf16u;
typedef __attribute__((ext_vector_type(8))) short bf16x8;
typedef __attribute__((ext_vector_type(4))) float f32x4;
typedef __attribute__((ext_vector_type(2))) float f32x2;

static __device__ inline bf16u f2bf(float f) {
    uint32 u = __float_as_uint(f);
    u += 0x7fff + ((u >> 16) & 1);          // round-nearest-even
    return (bf16u)(u >> 16);
}
static __device__ inline uint32 pack2(float a, float b) {
    return (uint32)f2bf(a) | ((uint32)f2bf(b) << 16);
}
static __device__ inline u8 f2fp8(float v) {
    uint32 p = __builtin_amdgcn_cvt_pk_fp8_f32(v, v, 0, false);
    return (u8)(p & 0xff);
}
static __device__ inline void acc_fp8x4(uint32 u, float& a0, float& a1,
                                        float& a2, float& a3) {
    f32x2 lo = __builtin_amdgcn_cvt_pk_f32_fp8((int)u, false);
    f32x2 hi = __builtin_amdgcn_cvt_pk_f32_fp8((int)u, true);
    a0 += lo.x; a1 += lo.y; a2 += hi.x; a3 += hi.y;
}

// neighbor-sum: ONE node per 16-lane group. lane c2=lane&15 owns channels
// 4*c2..4*c2+3. 4 gathers in flight per lane, no cross-lane reduction.
static __device__ inline void gather_group(
    const uint32* __restrict__ y8, const int* __restrict__ col,
    int rs, int re, int c2,
    float& a0, float& a1, float& a2, float& a3)
{
    int j = rs;
    for (; j + 4 <= re; j += 4) {
        int s0 = col[j];
        int s1 = col[j + 1];
        int s2 = col[j + 2];
        int s3 = col[j + 3];
        uint32 u0 = y8[s0 * 16 + c2];
        uint32 u1 = y8[s1 * 16 + c2];
        uint32 u2 = y8[s2 * 16 + c2];
        uint32 u3 = y8[s3 * 16 + c2];
        acc_fp8x4(u0, a0, a1, a2, a3);
        acc_fp8x4(u1, a0, a1, a2, a3);
        acc_fp8x4(u2, a0, a1, a2, a3);
        acc_fp8x4(u3, a0, a1, a2, a3);
    }
    for (; j < re; ++j) {
        uint32 u = y8[col[j] * 16 + c2];
        acc_fp8x4(u, a0, a1, a2, a3);
    }
}

// ---------- fused: degree count (atomic WITH return -> pos, coalesced) + lin0 ----
// count and lin0 are independent; fusing overlaps atomic-latency-bound
// counting with the HBM-bound x read and saves one dispatch.
__global__ __launch_bounds__(256, 6) void k_pre(
    const int* __restrict__ dst, int* __restrict__ cnt, int* __restrict__ pos,
    const float4* __restrict__ x4, const float* __restrict__ w,
    u8* __restrict__ y, int N, int E)
{
    int gt = blockIdx.x * 256 + threadIdx.x;
    for (int e = gt; e < E; e += gridDim.x * 256)
        pos[e] = atomicAdd(&cnt[dst[e]], 1);

    __shared__ __align__(16) uint32 t32[16 * 68];
    int tid = threadIdx.x;
    int wid = tid >> 6, lane = tid & 63;
    int quad = lane >> 4, n15 = lane & 15;
    int mycol = wid * 16 + n15;
    bf16x8 fb[4];
    #pragma unroll
    for (int s = 0; s < 4; s++)
        #pragma unroll
        for (int j = 0; j < 8; j++)
            fb[s][j] = (short)f2bf(w[(s * 32 + quad * 8 + j) * HID + mycol]);
    int snode = tid >> 4, sk = tid & 15;
    for (long g0 = (long)blockIdx.x * 16; g0 < N; g0 += (long)gridDim.x * 16) {
        long node = g0 + snode;
        if (node < N) {
            float4 v0 = x4[node * 32 + sk * 2];
            float4 v1 = x4[node * 32 + sk * 2 + 1];
            uint32 p[4] = {pack2(v0.x, v0.y), pack2(v0.z, v0.w),
                           pack2(v1.x, v1.y), pack2(v1.z, v1.w)};
            *(uint4*)((char*)t32 + snode * 272 + sk * 16) = *(uint4*)p;
        }
        __syncthreads();
        f32x4 acc = {0.f, 0.f, 0.f, 0.f};
        #pragma unroll
        for (int s = 0; s < 4; s++) {
            bf16x8 a = *(const bf16x8*)((const char*)t32 + n15 * 272 + s * 64 + quad * 16);
            acc = __builtin_amdgcn_mfma_f32_16x16x32_bf16(a, fb[s], acc, 0, 0, 0);
        }
        #pragma unroll
        for (int r = 0; r < 4; r++) {
            long n = g0 + quad * 4 + r;
            if (n < N) y[n * HID + mycol] = f2fp8(acc[r]);
        }
        __syncthreads();
    }
}

// ---------- single-kernel scan: cnt[N] -> row_ptr[N+1] ----------
__global__ __launch_bounds__(256) void k_scan(
    const int* __restrict__ cnt, int* __restrict__ row_ptr,
    int* __restrict__ partials, int* __restrict__ counter, int N, int E, int nch)
{
    __shared__ int red[256];
    int tid = threadIdx.x;
    int bid = blockIdx.x;
    long base = (long)bid * 1024 + tid * 4;
    int v[4]; int s = 0;
    #pragma unroll
    for (int i = 0; i < 4; i++) {
        long idx = base + i;
        v[i] = (idx < N) ? cnt[idx] : 0;
        s += v[i];
    }
    red[tid] = s;
    __syncthreads();
    for (int off = 1; off < 256; off <<= 1) {
        int t = (tid >= off) ? red[tid - off] : 0;
        __syncthreads();
        red[tid] += t;
        __syncthreads();
    }
    int myexcl = red[tid] - s;
    if (tid == 255) {
        __hip_atomic_store(&partials[bid], red[255], __ATOMIC_RELEASE,
                           __HIP_MEMORY_SCOPE_AGENT);
        atomicAdd(counter, 1);
    }
    if (tid == 0) {
        while (__hip_atomic_load(counter, __ATOMIC_ACQUIRE,
                                 __HIP_MEMORY_SCOPE_AGENT) < nch) { }
    }
    __syncthreads();
    int off = 0;
    for (int i = tid; i < bid; i += 256)
        off += __hip_atomic_load(&partials[i], __ATOMIC_RELAXED,
                                 __HIP_MEMORY_SCOPE_AGENT);
    __syncthreads();
    red[tid] = off;
    __syncthreads();
    for (int o = 128; o; o >>= 1) {
        if (tid < o) red[tid] += red[tid + o];
        __syncthreads();
    }
    int run = red[0] + myexcl;
    #pragma unroll
    for (int i = 0; i < 4; i++) {
        long idx = base + i;
        if (idx < N) row_ptr[idx] = run;
        run += v[i];
    }
    if (bid == 0 && tid == 0) row_ptr[N] = E;
}

// ---------- CSR place: atomic-free ----------
__global__ __launch_bounds__(256) void k_place(
    const int* __restrict__ src, const int* __restrict__ dst,
    const int* __restrict__ row_ptr, const int* __restrict__ pos,
    int* __restrict__ col, int E)
{
    int e = blockIdx.x * 256 + threadIdx.x;
    if (e >= E) return;
    col[row_ptr[dst[e]] + pos[e]] = src[e];
}

// ---------- agg0f (MFMA): t=relu((1+e)y0+Σnbr+b0a); y1=relu(t@w0b+b0b)@w1a ----
__global__ __launch_bounds__(256, 6) void k_agg0f(
    const uint32* __restrict__ y8, const int* __restrict__ row_ptr,
    const int* __restrict__ col, const float* __restrict__ epsp,
    const float* __restrict__ ba, const float* __restrict__ wb,
    const float* __restrict__ bb, const float* __restrict__ w1a,
    u8* __restrict__ y1, int N)
{
    __shared__ __align__(16) uint32 t32[16 * 36];
    __shared__ __align__(16) uint32 h32[16 * 36];
    int tid = threadIdx.x;
    int wid = tid >> 6, lane = tid & 63;
    int c2 = lane & 15, h = lane >> 4;
    int quad = lane >> 4, n15 = lane & 15;
    int n0 = wid * 4;
    int mycol = wid * 16 + n15;
    float e = 1.f + epsp[0];
    float4 bav = ((const float4*)ba)[c2];
    float bbv = bb[mycol];
    bf16x8 fb[2], f1[2];
    #pragma unroll
    for (int s = 0; s < 2; s++)
        #pragma unroll
        for (int j = 0; j < 8; j++) {
            fb[s][j] = (short)f2bf(wb[(s * 32 + quad * 8 + j) * HID + mycol]);
            f1[s][j] = (short)f2bf(w1a[(s * 32 + quad * 8 + j) * HID + mycol]);
        }
    for (long g0 = (long)blockIdx.x * 16; g0 < N; g0 += (long)gridDim.x * 16) {
        long node = g0 + n0 + h;        // each 16-lane group owns one node
        if (node < N) {
            int rs = row_ptr[node], re = row_ptr[node + 1];
            uint32 us = y8[node * 16 + c2];
            float a0 = 0.f, a1 = 0.f, a2 = 0.f, a3 = 0.f;
            gather_group(y8, col, rs, re, c2, a0, a1, a2, a3);
            f32x2 lo = __builtin_amdgcn_cvt_pk_f32_fp8((int)us, false);
            f32x2 hi = __builtin_amdgcn_cvt_pk_f32_fp8((int)us, true);
            a0 = fmaf(e, lo.x, a0); a1 = fmaf(e, lo.y, a1);
            a2 = fmaf(e, hi.x, a2); a3 = fmaf(e, hi.y, a3);
            t32[(n0 + h) * 36 + 2 * c2]     = pack2(fmaxf(a0 + bav.x, 0.f),
                                                    fmaxf(a1 + bav.y, 0.f));
            t32[(n0 + h) * 36 + 2 * c2 + 1] = pack2(fmaxf(a2 + bav.z, 0.f),
                                                    fmaxf(a3 + bav.w, 0.f));
        }
        __syncthreads();
        f32x4 acc = {bbv, bbv, bbv, bbv};
        {
            bf16x8 a0 = *(const bf16x8*)((const char*)t32 + n15 * 144 + quad * 16);
            bf16x8 a1 = *(const bf16x8*)((const char*)t32 + n15 * 144 + 64 + quad * 16);
            acc = __builtin_amdgcn_mfma_f32_16x16x32_bf16(a0, fb[0], acc, 0, 0, 0);
            acc = __builtin_amdgcn_mfma_f32_16x16x32_bf16(a1, fb[1], acc, 0, 0, 0);
        }
        #pragma unroll
        for (int r = 0; r < 4; r++)
            ((short*)h32)[(quad * 4 + r) * 72 + mycol] = (short)f2bf(fmaxf(acc[r], 0.f));
        __syncthreads();
        f32x4 acc2 = {0.f, 0.f, 0.f, 0.f};
        {
            bf16x8 a0 = *(const bf16x8*)((const char*)h32 + n15 * 144 + quad * 16);
            bf16x8 a1 = *(const bf16x8*)((const char*)h32 + n15 * 144 + 64 + quad * 16);
            acc2 = __builtin_amdgcn_mfma_f32_16x16x32_bf16(a0, f1[0], acc2, 0, 0, 0);
            acc2 = __builtin_amdgcn_mfma_f32_16x16x32_bf16(a1, f1[1], acc2, 0, 0, 0);
        }
        #pragma unroll
        for (int r = 0; r < 4; r++) {
            long n = g0 + quad * 4 + r;
            if (n < N) y1[n * HID + mycol] = f2fp8(acc2[r]);
        }
    }
}

// ---------- agg1 (MFMA): gather + MLP-b + pooling ----------
__global__ __launch_bounds__(256, 6) void k_agg1(
    const uint32* __restrict__ y8, const int* __restrict__ row_ptr,
    const int* __restrict__ col, const float* __restrict__ epsp,
    const float* __restrict__ ba, const float* __restrict__ wb,
    const float* __restrict__ bb, const int* __restrict__ batch,
    float* __restrict__ pooled, int N)
{
    __shared__ __align__(16) uint32 t32[16 * 36];
    int tid = threadIdx.x;
    int wid = tid >> 6, lane = tid & 63;
    int c2 = lane & 15, h = lane >> 4;
    int quad = lane >> 4, n15 = lane & 15;
    int n0 = wid * 4;
    int mycol = wid * 16 + n15;
    float e = 1.f + epsp[0];
    float4 bav = ((const float4*)ba)[c2];
    float bbv = bb[mycol];
    bf16x8 fb[2];
    #pragma unroll
    for (int s = 0; s < 2; s++)
        #pragma unroll
        for (int j = 0; j < 8; j++)
            fb[s][j] = (short)f2bf(wb[(s * 32 + quad * 8 + j) * HID + mycol]);
    for (long g0 = (long)blockIdx.x * 16; g0 < N; g0 += (long)gridDim.x * 16) {
        long node = g0 + n0 + h;        // each 16-lane group owns one node
        if (node < N) {
            int rs = row_ptr[node], re = row_ptr[node + 1];
            uint32 us = y8[node * 16 + c2];
            float a0 = 0.f, a1 = 0.f, a2 = 0.f, a3 = 0.f;
            gather_group(y8, col, rs, re, c2, a0, a1, a2, a3);
            f32x2 lo = __builtin_amdgcn_cvt_pk_f32_fp8((int)us, false);
            f32x2 hi = __builtin_amdgcn_cvt_pk_f32_fp8((int)us, true);
            a0 = fmaf(e, lo.x, a0); a1 = fmaf(e, lo.y, a1);
            a2 = fmaf(e, hi.x, a2); a3 = fmaf(e, hi.y, a3);
            t32[(n0 + h) * 36 + 2 * c2]     = pack2(fmaxf(a0 + bav.x, 0.f),
                                                    fmaxf(a1 + bav.y, 0.f));
            t32[(n0 + h) * 36 + 2 * c2 + 1] = pack2(fmaxf(a2 + bav.z, 0.f),
                                                    fmaxf(a3 + bav.w, 0.f));
        }
        __syncthreads();
        f32x4 acc = {bbv, bbv, bbv, bbv};
        {
            bf16x8 a0 = *(const bf16x8*)((const char*)t32 + n15 * 144 + quad * 16);
            bf16x8 a1 = *(const bf16x8*)((const char*)t32 + n15 * 144 + 64 + quad * 16);
            acc = __builtin_amdgcn_mfma_f32_16x16x32_bf16(a0, fb[0], acc, 0, 0, 0);
            acc = __builtin_amdgcn_mfma_f32_16x16x32_bf16(a1, fb[1], acc, 0, 0, 0);
        }
        float rv[4];
        #pragma unroll
        for (int r = 0; r < 4; r++) rv[r] = fmaxf(acc[r], 0.f);
        int nv = (int)((N - g0) < 16 ? (N - g0) : 16);
        int bf_ = batch[g0], bl_ = batch[g0 + nv - 1];
        if (bf_ == bl_) {
            float s = 0.f;
            #pragma unroll
            for (int r = 0; r < 4; r++)
                if (quad * 4 + r < nv) s += rv[r];
            s += __shfl_xor(s, 16);
            s += __shfl_xor(s, 32);
            if (quad == 0)
                atomicAdd(&pooled[(long)bf_ * HID + mycol], s);
        } else {
            #pragma unroll
            for (int r = 0; r < 4; r++) {
                long n = g0 + quad * 4 + r;
                if (n < N)
                    atomicAdd(&pooled[(long)batch[n] * HID + mycol], rv[r]);
            }
        }
        __syncthreads();
    }
}

// ---------- head ----------
__global__ __launch_bounds__(64) void k_head(
    const float* __restrict__ pooled, const float* __restrict__ fcw,
    const float* __restrict__ fcb, float* __restrict__ out)
{
    int g = blockIdx.x;
    int l = threadIdx.x;
    float logit = -INFINITY;
    if (l < OUT_CH) {
        float acc = fcb[l];
        #pragma unroll
        for (int k = 0; k < HID; k++)
            acc = fmaf(pooled[g * HID + k], fcw[k * OUT_CH + l], acc);
        logit = acc;
    }
    float m = logit;
    #pragma unroll
    for (int off = 32; off; off >>= 1) m = fmaxf(m, __shfl_xor(m, off));
    float ex = (l < OUT_CH) ? expf(logit - m) : 0.0f;
    float s = ex;
    #pragma unroll
    for (int off = 32; off; off >>= 1) s += __shfl_xor(s, off);
    if (l < OUT_CH) out[g * OUT_CH + l] = logit - m - logf(s);
}

extern "C" void kernel_launch(void* const* d_in, const int* in_sizes, int n_in,
                              void* d_out, int out_size, void* d_ws, size_t ws_size,
                              hipStream_t stream) {
    const float* x    = (const float*)d_in[0];
    const int*   ei   = (const int*)d_in[1];
    const int*   batch= (const int*)d_in[2];
    const float* eps0 = (const float*)d_in[3];
    const float* w0a  = (const float*)d_in[4];
    const float* b0a  = (const float*)d_in[5];
    const float* w0b  = (const float*)d_in[6];
    const float* b0b  = (const float*)d_in[7];
    const float* eps1 = (const float*)d_in[8];
    const float* w1a  = (const float*)d_in[9];
    const float* b1a  = (const float*)d_in[10];
    const float* w1b  = (const float*)d_in[11];
    const float* b1b  = (const float*)d_in[12];
    const float* fcw  = (const float*)d_in[13];
    const float* fcb  = (const float*)d_in[14];
    float* out = (float*)d_out;

    const int N = in_sizes[0] / IN_CH;       // 50000
    const int E = in_sizes[1] / 2;           // 800000
    const int G = out_size / OUT_CH;         // 512
    const int* src = ei;
    const int* dst = ei + E;

    // workspace layout (bytes):
    // [0, 200064)            row_ptr  (N+1 ints)
    // [200064, 3400064)      col      (E ints)
    // [3400064, 6600064)     y0       (N*64 fp8)
    // [6600064, 9800064)     y1       (N*64 fp8)
    // [9800064, 10000064)    cnt      (N ints)
    // [10000064, 10000068)   counter
    // [10000128, 10000384)   partials (49 ints, padded)
    // [10000384, 10131456)   pooled   (G*64 fp32)
    // [10131456, 13331456)   pos      (E ints)
    char* ws = (char*)d_ws;
    int*    row_ptr  = (int*)(ws);
    int*    colv     = (int*)(ws + 200064);
    u8*     y0       = (u8*)(ws + 3400064);
    u8*     y1       = (u8*)(ws + 6600064);
    int*    cnt      = (int*)(ws + 9800064);
    int*    counter  = (int*)(ws + 10000064);
    int*    partials = (int*)(ws + 10000128);
    float*  pooled   = (float*)(ws + 10000384);
    int*    pos      = (int*)(ws + 10131456);

    // one memset covers cnt + counter + partials + pooled
    hipMemsetAsync(cnt, 0, 331392, stream);

    int eb = (E + 255) / 256;                   // 3125
    int nb = (N + 31) / 32;                     // 1563
    int nch = (N + 1023) / 1024;                // 49 blocks, all co-resident
    k_pre<<<nb, 256, 0, stream>>>(dst, cnt, pos, (const float4*)x, w0a, y0, N, E);
    k_scan<<<nch, 256, 0, stream>>>(cnt, row_ptr, partials, counter, N, E, nch);
    k_place<<<eb, 256, 0, stream>>>(src, dst, row_ptr, pos, colv, E);

    k_agg0f<<<nb, 256, 0, stream>>>((const uint32*)y0, row_ptr, colv, eps0,
                                    b0a, w0b, b0b, w1a, y1, N);
    k_agg1<<<nb, 256, 0, stream>>>((const uint32*)y1, row_ptr, colv, eps1,
                                   b1a, w1b, b1b, batch, pooled, N);
    k_head<<<G, 64, 0, stream>>>(pooled, fcw, fcb, out);
}

// Round 10
// 195.240 us; speedup vs baseline: 1.1663x; 1.0184x over previous
//
#include <hip/hip_runtime.h>
#include <math.h>

#define IN_CH 128
#define HID 64
#define OUT_CH 10
#define LINB 1051   // blocks [0,LINB): lin0-only. [LINB,nb): count, then small lin0 share.
#define W_LIN 5     // lin0-only block weight  (≈40 nodes)
#define W_CNT 2     // count block lin0 weight (≈16 nodes)

typedef unsigned int uint32;
typedef unsigned char u8;
typedef unsigned short bf16u;
typedef __attribute__((ext_vector_type(8))) short bf16x8;
typedef __attribute__((ext_vector_type(4))) float f32x4;
typedef __attribute__((ext_vector_type(2))) float f32x2;

static __device__ inline bf16u f2bf(float f) {
    uint32 u = __float_as_uint(f);
    u += 0x7fff + ((u >> 16) & 1);          // round-nearest-even
    return (bf16u)(u >> 16);
}
static __device__ inline uint32 pack2(float a, float b) {
    return (uint32)f2bf(a) | ((uint32)f2bf(b) << 16);
}
static __device__ inline u8 f2fp8(float v) {
    uint32 p = __builtin_amdgcn_cvt_pk_fp8_f32(v, v, 0, false);
    return (u8)(p & 0xff);
}
static __device__ inline void acc_fp8x4(uint32 u, float& a0, float& a1,
                                        float& a2, float& a3) {
    f32x2 lo = __builtin_amdgcn_cvt_pk_f32_fp8((int)u, false);
    f32x2 hi = __builtin_amdgcn_cvt_pk_f32_fp8((int)u, true);
    a0 += lo.x; a1 += lo.y; a2 += hi.x; a3 += hi.y;
}

// neighbor-sum: ONE node per 16-lane group. lane c2=lane&15 owns channels
// 4*c2..4*c2+3. 4 gathers in flight per lane, no cross-lane reduction.
static __device__ inline void gather_group(
    const uint32* __restrict__ y8, const int* __restrict__ col,
    int rs, int re, int c2,
    float& a0, float& a1, float& a2, float& a3)
{
    int j = rs;
    for (; j + 4 <= re; j += 4) {
        int s0 = col[j];
        int s1 = col[j + 1];
        int s2 = col[j + 2];
        int s3 = col[j + 3];
        uint32 u0 = y8[s0 * 16 + c2];
        uint32 u1 = y8[s1 * 16 + c2];
        uint32 u2 = y8[s2 * 16 + c2];
        uint32 u3 = y8[s3 * 16 + c2];
        acc_fp8x4(u0, a0, a1, a2, a3);
        acc_fp8x4(u1, a0, a1, a2, a3);
        acc_fp8x4(u2, a0, a1, a2, a3);
        acc_fp8x4(u3, a0, a1, a2, a3);
    }
    for (; j < re; ++j) {
        uint32 u = y8[col[j] * 16 + c2];
        acc_fp8x4(u, a0, a1, a2, a3);
    }
}

// ---------- fused count || lin0, STATIC block specialization ----------
// Count is device-wide atomic-throughput-bound (~20us regardless of width):
// give it 512 blocks. lin0 groups are statically partitioned by weight so
// count blocks get a ~2.5x smaller lin0 share; all ~1563 blocks are
// co-resident, so lin0-only blocks run from t=0 while count atomics drain
// -> max() overlap with ZERO added sync (R3's work-steal atomic and R4's
// spin both regressed; this has neither).
__global__ __launch_bounds__(256, 6) void k_pre(
    const int* __restrict__ dst, int* __restrict__ cnt, int* __restrict__ pos,
    const float4* __restrict__ x4, const float* __restrict__ w,
    u8* __restrict__ y, int N, int E, int nb)
{
    int tid = threadIdx.x;
    int bid = blockIdx.x;
    if (bid >= LINB) {
        int ncb = nb - LINB;
        for (int e = (bid - LINB) * 256 + tid; e < E; e += ncb * 256)
            pos[e] = atomicAdd(&cnt[dst[e]], 1);
    }

    __shared__ __align__(16) uint32 t32[16 * 68];
    int wid = tid >> 6, lane = tid & 63;
    int quad = lane >> 4, n15 = lane & 15;
    int mycol = wid * 16 + n15;
    bf16x8 fb[4];
    #pragma unroll
    for (int s = 0; s < 4; s++)
        #pragma unroll
        for (int j = 0; j < 8; j++)
            fb[s][j] = (short)f2bf(w[(s * 32 + quad * 8 + j) * HID + mycol]);
    int snode = tid >> 4, sk = tid & 15;

    // weighted contiguous group range for this block
    int NG = (N + 15) >> 4;
    long TW   = (long)LINB * W_LIN + (long)(nb - LINB) * W_CNT;
    long cum0 = (bid <= LINB) ? (long)bid * W_LIN
                              : (long)LINB * W_LIN + (long)(bid - LINB) * W_CNT;
    long cum1 = cum0 + ((bid < LINB) ? W_LIN : W_CNT);
    int gs = (int)(cum0 * NG / TW);
    int ge = (int)(cum1 * NG / TW);

    for (int g = gs; g < ge; ++g) {
        long g0 = (long)g * 16;
        long node = g0 + snode;
        if (node < N) {
            float4 v0 = x4[node * 32 + sk * 2];
            float4 v1 = x4[node * 32 + sk * 2 + 1];
            uint32 p[4] = {pack2(v0.x, v0.y), pack2(v0.z, v0.w),
                           pack2(v1.x, v1.y), pack2(v1.z, v1.w)};
            *(uint4*)((char*)t32 + snode * 272 + sk * 16) = *(uint4*)p;
        }
        __syncthreads();
        f32x4 acc = {0.f, 0.f, 0.f, 0.f};
        #pragma unroll
        for (int s = 0; s < 4; s++) {
            bf16x8 a = *(const bf16x8*)((const char*)t32 + n15 * 272 + s * 64 + quad * 16);
            acc = __builtin_amdgcn_mfma_f32_16x16x32_bf16(a, fb[s], acc, 0, 0, 0);
        }
        #pragma unroll
        for (int r = 0; r < 4; r++) {
            long n = g0 + quad * 4 + r;
            if (n < N) y[n * HID + mycol] = f2fp8(acc[r]);
        }
        __syncthreads();
    }
}

// ---------- single-kernel scan: cnt[N] -> row_ptr[N+1] ----------
__global__ __launch_bounds__(256) void k_scan(
    const int* __restrict__ cnt, int* __restrict__ row_ptr,
    int* __restrict__ partials, int* __restrict__ counter, int N, int E, int nch)
{
    __shared__ int red[256];
    int tid = threadIdx.x;
    int bid = blockIdx.x;
    long base = (long)bid * 1024 + tid * 4;
    int v[4]; int s = 0;
    #pragma unroll
    for (int i = 0; i < 4; i++) {
        long idx = base + i;
        v[i] = (idx < N) ? cnt[idx] : 0;
        s += v[i];
    }
    red[tid] = s;
    __syncthreads();
    for (int off = 1; off < 256; off <<= 1) {
        int t = (tid >= off) ? red[tid - off] : 0;
        __syncthreads();
        red[tid] += t;
        __syncthreads();
    }
    int myexcl = red[tid] - s;
    if (tid == 255) {
        __hip_atomic_store(&partials[bid], red[255], __ATOMIC_RELEASE,
                           __HIP_MEMORY_SCOPE_AGENT);
        atomicAdd(counter, 1);
    }
    if (tid == 0) {
        while (__hip_atomic_load(counter, __ATOMIC_ACQUIRE,
                                 __HIP_MEMORY_SCOPE_AGENT) < nch) { }
    }
    __syncthreads();
    int off = 0;
    for (int i = tid; i < bid; i += 256)
        off += __hip_atomic_load(&partials[i], __ATOMIC_RELAXED,
                                 __HIP_MEMORY_SCOPE_AGENT);
    __syncthreads();
    red[tid] = off;
    __syncthreads();
    for (int o = 128; o; o >>= 1) {
        if (tid < o) red[tid] += red[tid + o];
        __syncthreads();
    }
    int run = red[0] + myexcl;
    #pragma unroll
    for (int i = 0; i < 4; i++) {
        long idx = base + i;
        if (idx < N) row_ptr[idx] = run;
        run += v[i];
    }
    if (bid == 0 && tid == 0) row_ptr[N] = E;
}

// ---------- CSR place: atomic-free ----------
__global__ __launch_bounds__(256) void k_place(
    const int* __restrict__ src, const int* __restrict__ dst,
    const int* __restrict__ row_ptr, const int* __restrict__ pos,
    int* __restrict__ col, int E)
{
    int e = blockIdx.x * 256 + threadIdx.x;
    if (e >= E) return;
    col[row_ptr[dst[e]] + pos[e]] = src[e];
}

// ---------- agg0f (MFMA): t=relu((1+e)y0+Σnbr+b0a); y1=relu(t@w0b+b0b)@w1a ----
__global__ __launch_bounds__(256, 6) void k_agg0f(
    const uint32* __restrict__ y8, const int* __restrict__ row_ptr,
    const int* __restrict__ col, const float* __restrict__ epsp,
    const float* __restrict__ ba, const float* __restrict__ wb,
    const float* __restrict__ bb, const float* __restrict__ w1a,
    u8* __restrict__ y1, int N)
{
    __shared__ __align__(16) uint32 t32[16 * 36];
    __shared__ __align__(16) uint32 h32[16 * 36];
    int tid = threadIdx.x;
    int wid = tid >> 6, lane = tid & 63;
    int c2 = lane & 15, h = lane >> 4;
    int quad = lane >> 4, n15 = lane & 15;
    int n0 = wid * 4;
    int mycol = wid * 16 + n15;
    float e = 1.f + epsp[0];
    float4 bav = ((const float4*)ba)[c2];
    float bbv = bb[mycol];
    bf16x8 fb[2], f1[2];
    #pragma unroll
    for (int s = 0; s < 2; s++)
        #pragma unroll
        for (int j = 0; j < 8; j++) {
            fb[s][j] = (short)f2bf(wb[(s * 32 + quad * 8 + j) * HID + mycol]);
            f1[s][j] = (short)f2bf(w1a[(s * 32 + quad * 8 + j) * HID + mycol]);
        }
    for (long g0 = (long)blockIdx.x * 16; g0 < N; g0 += (long)gridDim.x * 16) {
        long node = g0 + n0 + h;        // each 16-lane group owns one node
        if (node < N) {
            int rs = row_ptr[node], re = row_ptr[node + 1];
            uint32 us = y8[node * 16 + c2];
            float a0 = 0.f, a1 = 0.f, a2 = 0.f, a3 = 0.f;
            gather_group(y8, col, rs, re, c2, a0, a1, a2, a3);
            f32x2 lo = __builtin_amdgcn_cvt_pk_f32_fp8((int)us, false);
            f32x2 hi = __builtin_amdgcn_cvt_pk_f32_fp8((int)us, true);
            a0 = fmaf(e, lo.x, a0); a1 = fmaf(e, lo.y, a1);
            a2 = fmaf(e, hi.x, a2); a3 = fmaf(e, hi.y, a3);
            t32[(n0 + h) * 36 + 2 * c2]     = pack2(fmaxf(a0 + bav.x, 0.f),
                                                    fmaxf(a1 + bav.y, 0.f));
            t32[(n0 + h) * 36 + 2 * c2 + 1] = pack2(fmaxf(a2 + bav.z, 0.f),
                                                    fmaxf(a3 + bav.w, 0.f));
        }
        __syncthreads();
        f32x4 acc = {bbv, bbv, bbv, bbv};
        {
            bf16x8 a0 = *(const bf16x8*)((const char*)t32 + n15 * 144 + quad * 16);
            bf16x8 a1 = *(const bf16x8*)((const char*)t32 + n15 * 144 + 64 + quad * 16);
            acc = __builtin_amdgcn_mfma_f32_16x16x32_bf16(a0, fb[0], acc, 0, 0, 0);
            acc = __builtin_amdgcn_mfma_f32_16x16x32_bf16(a1, fb[1], acc, 0, 0, 0);
        }
        #pragma unroll
        for (int r = 0; r < 4; r++)
            ((short*)h32)[(quad * 4 + r) * 72 + mycol] = (short)f2bf(fmaxf(acc[r], 0.f));
        __syncthreads();
        f32x4 acc2 = {0.f, 0.f, 0.f, 0.f};
        {
            bf16x8 a0 = *(const bf16x8*)((const char*)h32 + n15 * 144 + quad * 16);
            bf16x8 a1 = *(const bf16x8*)((const char*)h32 + n15 * 144 + 64 + quad * 16);
            acc2 = __builtin_amdgcn_mfma_f32_16x16x32_bf16(a0, f1[0], acc2, 0, 0, 0);
            acc2 = __builtin_amdgcn_mfma_f32_16x16x32_bf16(a1, f1[1], acc2, 0, 0, 0);
        }
        #pragma unroll
        for (int r = 0; r < 4; r++) {
            long n = g0 + quad * 4 + r;
            if (n < N) y1[n * HID + mycol] = f2fp8(acc2[r]);
        }
    }
}

// ---------- agg1 (MFMA): gather + MLP-b + pooling ----------
__global__ __launch_bounds__(256, 6) void k_agg1(
    const uint32* __restrict__ y8, const int* __restrict__ row_ptr,
    const int* __restrict__ col, const float* __restrict__ epsp,
    const float* __restrict__ ba, const float* __restrict__ wb,
    const float* __restrict__ bb, const int* __restrict__ batch,
    float* __restrict__ pooled, int N)
{
    __shared__ __align__(16) uint32 t32[16 * 36];
    int tid = threadIdx.x;
    int wid = tid >> 6, lane = tid & 63;
    int c2 = lane & 15, h = lane >> 4;
    int quad = lane >> 4, n15 = lane & 15;
    int n0 = wid * 4;
    int mycol = wid * 16 + n15;
    float e = 1.f + epsp[0];
    float4 bav = ((const float4*)ba)[c2];
    float bbv = bb[mycol];
    bf16x8 fb[2];
    #pragma unroll
    for (int s = 0; s < 2; s++)
        #pragma unroll
        for (int j = 0; j < 8; j++)
            fb[s][j] = (short)f2bf(wb[(s * 32 + quad * 8 + j) * HID + mycol]);
    for (long g0 = (long)blockIdx.x * 16; g0 < N; g0 += (long)gridDim.x * 16) {
        long node = g0 + n0 + h;        // each 16-lane group owns one node
        if (node < N) {
            int rs = row_ptr[node], re = row_ptr[node + 1];
            uint32 us = y8[node * 16 + c2];
            float a0 = 0.f, a1 = 0.f, a2 = 0.f, a3 = 0.f;
            gather_group(y8, col, rs, re, c2, a0, a1, a2, a3);
            f32x2 lo = __builtin_amdgcn_cvt_pk_f32_fp8((int)us, false);
            f32x2 hi = __builtin_amdgcn_cvt_pk_f32_fp8((int)us, true);
            a0 = fmaf(e, lo.x, a0); a1 = fmaf(e, lo.y, a1);
            a2 = fmaf(e, hi.x, a2); a3 = fmaf(e, hi.y, a3);
            t32[(n0 + h) * 36 + 2 * c2]     = pack2(fmaxf(a0 + bav.x, 0.f),
                                                    fmaxf(a1 + bav.y, 0.f));
            t32[(n0 + h) * 36 + 2 * c2 + 1] = pack2(fmaxf(a2 + bav.z, 0.f),
                                                    fmaxf(a3 + bav.w, 0.f));
        }
        __syncthreads();
        f32x4 acc = {bbv, bbv, bbv, bbv};
        {
            bf16x8 a0 = *(const bf16x8*)((const char*)t32 + n15 * 144 + quad * 16);
            bf16x8 a1 = *(const bf16x8*)((const char*)t32 + n15 * 144 + 64 + quad * 16);
            acc = __builtin_amdgcn_mfma_f32_16x16x32_bf16(a0, fb[0], acc, 0, 0, 0);
            acc = __builtin_amdgcn_mfma_f32_16x16x32_bf16(a1, fb[1], acc, 0, 0, 0);
        }
        float rv[4];
        #pragma unroll
        for (int r = 0; r < 4; r++) rv[r] = fmaxf(acc[r], 0.f);
        int nv = (int)((N - g0) < 16 ? (N - g0) : 16);
        int bf_ = batch[g0], bl_ = batch[g0 + nv - 1];
        if (bf_ == bl_) {
            float s = 0.f;
            #pragma unroll
            for (int r = 0; r < 4; r++)
                if (quad * 4 + r < nv) s += rv[r];
            s += __shfl_xor(s, 16);
            s += __shfl_xor(s, 32);
            if (quad == 0)
                atomicAdd(&pooled[(long)bf_ * HID + mycol], s);
        } else {
            #pragma unroll
            for (int r = 0; r < 4; r++) {
                long n = g0 + quad * 4 + r;
                if (n < N)
                    atomicAdd(&pooled[(long)batch[n] * HID + mycol], rv[r]);
            }
        }
        __syncthreads();
    }
}

// ---------- head ----------
__global__ __launch_bounds__(64) void k_head(
    const float* __restrict__ pooled, const float* __restrict__ fcw,
    const float* __restrict__ fcb, float* __restrict__ out)
{
    int g = blockIdx.x;
    int l = threadIdx.x;
    float logit = -INFINITY;
    if (l < OUT_CH) {
        float acc = fcb[l];
        #pragma unroll
        for (int k = 0; k < HID; k++)
            acc = fmaf(pooled[g * HID + k], fcw[k * OUT_CH + l], acc);
        logit = acc;
    }
    float m = logit;
    #pragma unroll
    for (int off = 32; off; off >>= 1) m = fmaxf(m, __shfl_xor(m, off));
    float ex = (l < OUT_CH) ? expf(logit - m) : 0.0f;
    float s = ex;
    #pragma unroll
    for (int off = 32; off; off >>= 1) s += __shfl_xor(s, off);
    if (l < OUT_CH) out[g * OUT_CH + l] = logit - m - logf(s);
}

extern "C" void kernel_launch(void* const* d_in, const int* in_sizes, int n_in,
                              void* d_out, int out_size, void* d_ws, size_t ws_size,
                              hipStream_t stream) {
    const float* x    = (const float*)d_in[0];
    const int*   ei   = (const int*)d_in[1];
    const int*   batch= (const int*)d_in[2];
    const float* eps0 = (const float*)d_in[3];
    const float* w0a  = (const float*)d_in[4];
    const float* b0a  = (const float*)d_in[5];
    const float* w0b  = (const float*)d_in[6];
    const float* b0b  = (const float*)d_in[7];
    const float* eps1 = (const float*)d_in[8];
    const float* w1a  = (const float*)d_in[9];
    const float* b1a  = (const float*)d_in[10];
    const float* w1b  = (const float*)d_in[11];
    const float* b1b  = (const float*)d_in[12];
    const float* fcw  = (const float*)d_in[13];
    const float* fcb  = (const float*)d_in[14];
    float* out = (float*)d_out;

    const int N = in_sizes[0] / IN_CH;       // 50000
    const int E = in_sizes[1] / 2;           // 800000
    const int G = out_size / OUT_CH;         // 512
    const int* src = ei;
    const int* dst = ei + E;

    // workspace layout (bytes):
    // [0, 200064)            row_ptr  (N+1 ints)
    // [200064, 3400064)      col      (E ints)
    // [3400064, 6600064)     y0       (N*64 fp8)
    // [6600064, 9800064)     y1       (N*64 fp8)
    // [9800064, 10000064)    cnt      (N ints)
    // [10000064, 10000068)   counter
    // [10000128, 10000384)   partials (49 ints, padded)
    // [10000384, 10131456)   pooled   (G*64 fp32)
    // [10131456, 13331456)   pos      (E ints)
    char* ws = (char*)d_ws;
    int*    row_ptr  = (int*)(ws);
    int*    colv     = (int*)(ws + 200064);
    u8*     y0       = (u8*)(ws + 3400064);
    u8*     y1       = (u8*)(ws + 6600064);
    int*    cnt      = (int*)(ws + 9800064);
    int*    counter  = (int*)(ws + 10000064);
    int*    partials = (int*)(ws + 10000128);
    float*  pooled   = (float*)(ws + 10000384);
    int*    pos      = (int*)(ws + 10131456);

    // one memset covers cnt + counter + partials + pooled
    hipMemsetAsync(cnt, 0, 331392, stream);

    int eb = (E + 255) / 256;                   // 3125
    int nb = (N + 31) / 32;                     // 1563
    int nch = (N + 1023) / 1024;                // 49 blocks, all co-resident
    k_pre<<<nb, 256, 0, stream>>>(dst, cnt, pos, (const float4*)x, w0a, y0,
                                  N, E, nb);
    k_scan<<<nch, 256, 0, stream>>>(cnt, row_ptr, partials, counter, N, E, nch);
    k_place<<<eb, 256, 0, stream>>>(src, dst, row_ptr, pos, colv, E);

    k_agg0f<<<nb, 256, 0, stream>>>((const uint32*)y0, row_ptr, colv, eps0,
                                    b0a, w0b, b0b, w1a, y1, N);
    k_agg1<<<nb, 256, 0, stream>>>((const uint32*)y1, row_ptr, colv, eps1,
                                   b1a, w1b, b1b, batch, pooled, N);
    k_head<<<G, 64, 0, stream>>>(pooled, fcw, fcb, out);
}